// Round 9
// baseline (289.187 us; speedup 1.0000x reference)
//
#include <hip/hip_runtime.h>
#include <hip/hip_bf16.h>
#include <stdint.h>

// ---------------------------------------------------------------------------
// CrossModalAttention: B=2, Tq=Tk=2048, DIM=1024, HEADS=16, HEAD_DIM=64
// f32 in/out; bf16 MFMA compute.
// R16 = R15 - setprio (measured neutral, +8 VGPR) + sbfe-AND softmax mask:
// p = bitcast(exp2(s)) & sbfe(maskword, off, 1)  -- replaces bfe+cvt+mul
// (5 ops/elem -> 4 at ~90% combined issue utilization), per-nt shift folded
// into the sbfe offset. Bisects R10's NaN: {sbfe} vs {cvt_pk asm} -- the V
// chunk-image layout was already exonerated by R11.
// cvt+pack fused (R15); GEMMs byte-identical.
// V-projection GEMM epilogue stores V^T in attn LDS-image chunk order
// (16B chunk = rows (d,d+16) x 4 tokens) so attn V staging is linear
// global_load_lds and V reads are conflict-free ds_read_b128.
// ---------------------------------------------------------------------------

typedef __bf16 bf16;
typedef __bf16 bf16x4 __attribute__((ext_vector_type(4)));
typedef __bf16 bf16x8 __attribute__((ext_vector_type(8)));
typedef float f32x4 __attribute__((ext_vector_type(4)));
typedef short s16x4 __attribute__((ext_vector_type(4)));

#define MFMA_BF16(a, b, c) __builtin_amdgcn_mfma_f32_16x16x32_bf16((a), (b), (c), 0, 0, 0)

__device__ __forceinline__ f32x4 mfma16(bf16x4 a, bf16x4 b, f32x4 c) {
  return __builtin_amdgcn_mfma_f32_16x16x16bf16_1k(
      __builtin_bit_cast(s16x4, a), __builtin_bit_cast(s16x4, b), c, 0, 0, 0);
}

// async global->LDS, 16B per lane (wave-uniform base, lane i at base+i*16)
__device__ __forceinline__ void async_load16(const void* g, void* l) {
  __builtin_amdgcn_global_load_lds((const __attribute__((address_space(1))) void*)g,
                                   (__attribute__((address_space(3))) void*)l, 16, 0, 0);
}

// ---------------------------------------------------------------------------
// 0) fused f32->bf16 conversion (z=0..6) + mask bit-pack (z=7).
//    grid = (1024, 8), grid-stride in each plane.
// ---------------------------------------------------------------------------
__global__ __launch_bounds__(256) void cvt_pack_kernel(
    const float* __restrict__ s0, const float* __restrict__ s1, const float* __restrict__ s2,
    const float* __restrict__ s3, const float* __restrict__ s4, const float* __restrict__ s5,
    const float* __restrict__ s6,
    bf16* __restrict__ d0, bf16* __restrict__ d1, bf16* __restrict__ d2,
    bf16* __restrict__ d3, bf16* __restrict__ d4, bf16* __restrict__ d5,
    bf16* __restrict__ d6,
    const int* __restrict__ mask, unsigned long long* __restrict__ bits) {
  const int z = blockIdx.y;
  if (z == 7) {
    // mask pack: t indexes int4 -> values 4t..4t+3 -> bits 4*(t&15)+j of
    // word t>>4. stride is a multiple of 16 so t&15 == tid&15 invariantly.
    const int total4 = 8388608 / 4;
    const int stride = gridDim.x * 256;
    for (int t = blockIdx.x * 256 + threadIdx.x; t < total4; t += stride) {
      const int4 v = ((const int4*)mask)[t];
      uint32_t wrd = (v.x != 0 ? 1u : 0u) | (v.y != 0 ? 2u : 0u) |
                     (v.z != 0 ? 4u : 0u) | (v.w != 0 ? 8u : 0u);
      wrd <<= 4 * (threadIdx.x & 7);
      wrd |= __shfl_xor((int)wrd, 1);
      wrd |= __shfl_xor((int)wrd, 2);
      wrd |= __shfl_xor((int)wrd, 4);
      const uint32_t other = (uint32_t)__shfl_xor((int)wrd, 8);
      if ((threadIdx.x & 15) == 0)
        bits[t >> 4] = (unsigned long long)wrd | ((unsigned long long)other << 32);
    }
    return;
  }
  const float* s = (z == 0) ? s0 : (z == 1) ? s1 : (z == 2) ? s2 : (z == 3) ? s3
                   : (z == 4) ? s4 : (z == 5) ? s5 : s6;
  bf16* d = (z == 0) ? d0 : (z == 1) ? d1 : (z == 2) ? d2 : (z == 3) ? d3
            : (z == 4) ? d4 : (z == 5) ? d5 : d6;
  const int n4 = (z < 3) ? (4 * 1024 * 1024 / 4) : (1024 * 1024 / 4);
  const int stride = gridDim.x * 256;
  for (int i = blockIdx.x * 256 + threadIdx.x; i < n4; i += stride) {
    const float4 v = ((const float4*)s)[i];
    bf16x4 o;
    o[0] = (bf16)v.x; o[1] = (bf16)v.y; o[2] = (bf16)v.z; o[3] = (bf16)v.w;
    ((bf16x4*)d)[i] = o;
  }
}

// ---------------------------------------------------------------------------
// 2/4) GEMM C[m,n] = sum_k X[m,k]*W[n,k] + bias[n]  (m97 K-loop)
//      qs: extra output scale applied only for z==0 bf16 path (Q projection).
//      z==vz: V^T written in attn LDS-image chunk layout (see header).
// ---------------------------------------------------------------------------
__global__ __launch_bounds__(256) void gemm_bt_bias(
    const bf16* __restrict__ X0, const bf16* __restrict__ X1, const bf16* __restrict__ X2,
    const bf16* __restrict__ W0, const bf16* __restrict__ W1, const bf16* __restrict__ W2,
    const float* __restrict__ Bi0, const float* __restrict__ Bi1, const float* __restrict__ Bi2,
    bf16* __restrict__ O0, bf16* __restrict__ O1, bf16* __restrict__ O2,
    float* __restrict__ OF, int K, int N, int vz, int f32out, float qs) {
  const int z = blockIdx.z;
  const bf16* X   = (z == 0) ? X0  : (z == 1) ? X1  : X2;
  const bf16* W   = (z == 0) ? W0  : (z == 1) ? W1  : W2;
  const float* Bi = (z == 0) ? Bi0 : (z == 1) ? Bi1 : Bi2;
  bf16* O         = (z == 0) ? O0  : (z == 1) ? O1  : O2;

  __shared__ __align__(16) unsigned char smem_raw[34816];
  bf16* As  = (bf16*)smem_raw;
  bf16* Bs  = As + 128 * 64;
  bf16* Tt  = (bf16*)smem_raw;   // bf16 tile, stride 136
  float* Tf = (float*)smem_raw;  // f32 half-tile (64 rows), stride 132

  const int tid = threadIdx.x;
  const int lane = tid & 63;
  const int w = tid >> 6;
  const int la = lane & 15;
  const int qa = lane >> 4;
  const int m0 = blockIdx.x * 128;
  const int n0 = blockIdx.y * 128;
  const int wm = (w & 1) * 64;
  const int wn = (w >> 1) * 64;

  f32x4 acc[4][4];
  for (int i = 0; i < 4; ++i)
    for (int j = 0; j < 4; ++j) acc[i][j] = (f32x4){0.f, 0.f, 0.f, 0.f};

  for (int k0 = 0; k0 < K; k0 += 64) {
    for (int i = 0; i < 4; ++i) {
      const int cb = i * 256 + w * 64;
      const int c = cb + lane;
      const int row = c >> 3;
      const int cc = (c & 7) * 8;
      async_load16(X + (size_t)(m0 + row) * K + k0 + cc, As + (size_t)cb * 8);
      async_load16(W + (size_t)(n0 + row) * K + k0 + cc, Bs + (size_t)cb * 8);
    }
    __syncthreads();
    for (int kk = 0; kk < 64; kk += 32) {
      bf16x8 af[4], bfr[4];
      for (int mt = 0; mt < 4; ++mt)
        af[mt] = *(const bf16x8*)&As[(wm + mt * 16 + la) * 64 + kk + qa * 8];
      for (int nt = 0; nt < 4; ++nt)
        bfr[nt] = *(const bf16x8*)&Bs[(wn + nt * 16 + la) * 64 + kk + qa * 8];
      for (int mt = 0; mt < 4; ++mt)
        for (int nt = 0; nt < 4; ++nt)
          acc[mt][nt] = MFMA_BF16(af[mt], bfr[nt], acc[mt][nt]);
    }
    __syncthreads();
  }

  if (f32out) {
    for (int pass = 0; pass < 2; ++pass) {
      if ((w & 1) == pass) {
        for (int mt = 0; mt < 4; ++mt)
          for (int nt = 0; nt < 4; ++nt)
            for (int r = 0; r < 4; ++r) {
              const int rl = mt * 16 + qa * 4 + r;
              const int cl = wn + nt * 16 + la;
              Tf[rl * 132 + cl] = acc[mt][nt][r] + Bi[n0 + cl];
            }
      }
      __syncthreads();
      for (int i = 0; i < 8; ++i) {
        const int rl = i * 8 + (tid >> 5);
        const int cl = (tid & 31) * 4;
        const float4 vv = *(const float4*)&Tf[rl * 132 + cl];
        *(float4*)&OF[(size_t)(m0 + pass * 64 + rl) * N + n0 + cl] = vv;
      }
      __syncthreads();
    }
  } else if (z != vz) {
    const float sc = (z == 0) ? qs : 1.0f;
    for (int mt = 0; mt < 4; ++mt)
      for (int nt = 0; nt < 4; ++nt)
        for (int r = 0; r < 4; ++r) {
          const int rl = wm + mt * 16 + qa * 4 + r;
          const int cl = wn + nt * 16 + la;
          Tt[rl * 136 + cl] = (bf16)((acc[mt][nt][r] + Bi[n0 + cl]) * sc);
        }
    __syncthreads();
    for (int i = 0; i < 8; ++i) {
      const int rl = i * 16 + (tid >> 4);
      const int cc = (tid & 15) * 8;
      *(bf16x8*)&O[(size_t)(m0 + rl) * N + n0 + cc] = *(const bf16x8*)&Tt[rl * 136 + cc];
    }
  } else {
    // V^T in LDS (d-major), then chunked attn LDS-image layout to global.
    for (int mt = 0; mt < 4; ++mt)
      for (int nt = 0; nt < 4; ++nt)
        for (int r = 0; r < 4; ++r) {
          const int rl = wm + mt * 16 + qa * 4 + r;
          const int cl = wn + nt * 16 + la;
          Tt[cl * 136 + rl] = (bf16)(acc[mt][nt][r] + Bi[n0 + cl]);
        }
    __syncthreads();
    const int bb = m0 >> 11;
    const int kt0 = (m0 & 2047) >> 6;  // first of 2 token-tiles in this block
    const int h0 = n0 >> 6;            // first of 2 heads in this block
    // 2048 chunks of 16B: gi = (hb<<10)|(ktb<<9)|c ; c = (dt2*4+nt)*64 + sig,
    // sig = (la&7) + 8*(qa + 4*(la>>3)). Chunk = rows {dt2*32+lac, +16} x
    // tokens ktb*64 + nt*16 + qa*4 + 0..3.
    for (int i = 0; i < 8; ++i) {
      const int gi = i * 256 + tid;
      const int c = gi & 511;
      const int ktb = (gi >> 9) & 1;
      const int hb = gi >> 10;
      const int dt2 = (c >> 8) & 1;
      const int ntc = (c >> 6) & 3;
      const int tq = (c >> 3) & 7;
      const int qac = tq & 3;
      const int lac = ((tq >> 2) << 3) + (c & 7);
      const int clA = hb * 64 + dt2 * 32 + lac;
      const int rlb = ktb * 64 + ntc * 16 + qac * 4;
      const bf16x4 lo4 = *(const bf16x4*)&Tt[clA * 136 + rlb];
      const bf16x4 hi4 = *(const bf16x4*)&Tt[(clA + 16) * 136 + rlb];
      bf16x8 outc;
      for (int j = 0; j < 4; ++j) { outc[j] = lo4[j]; outc[j + 4] = hi4[j]; }
      const size_t g16 = ((size_t)((bb * 16 + h0 + hb) * 32) + kt0 + ktb) * 512 + c;
      *(bf16x8*)&O[g16 * 8] = outc;
    }
  }
}

// ---------------------------------------------------------------------------
// 3) fused attention (R11 + sbfe-AND mask). grid = (Tq/64, B*H), 4 waves x
//    16 q-rows, KT=64, 32 iterations, one barrier/iter, async double-buffer.
//    K tile XOR-swizzled (pre-swizzled global source); V tile staged linearly
//    (global buffer is the LDS image), read as 8x conflict-free ds_read_b128.
//    Softmax: p = bits(exp2(s)) & sbfe(word, (nt&1)*16+r, 1); Q pre-scaled.
// ---------------------------------------------------------------------------
__global__ __launch_bounds__(256, 3) void attn_kernel(
    const bf16* __restrict__ Qp, const bf16* __restrict__ Kp, const bf16* __restrict__ Vt,
    const unsigned long long* __restrict__ mbits, bf16* __restrict__ AO) {
  __shared__ bf16 Kb[2][64 * 64];  // [kcol][d], XOR-swizzled chunks
  __shared__ bf16 Vb[2][64 * 64];  // chunk-image layout (see GEMM epilogue)

  const int tid = threadIdx.x;
  const int lane = tid & 63;
  const int w = tid >> 6;
  const int la = lane & 15;
  const int qa = lane >> 4;
  const int la7 = la & 7;
  const int b = blockIdx.y >> 4;
  const int h = blockIdx.y & 15;
  const int q0 = blockIdx.x * 64 + w * 16;  // this wave's 16 q-rows

  const size_t kbase = (size_t)(b * 2048) * 1024 + h * 64;
  const unsigned long long* mrow = mbits + ((size_t)(b * 2048 + q0 + la)) * 32;

  // staging geometry: 512 chunks of 16B per tile, 2 per thread
  const int cb0 = w * 64;
  const int cb1 = 256 + w * 64;
  const int c0 = cb0 + lane, c1 = cb1 + lane;
  // K source: XOR-swizzled chunks (slot c holds global chunk (r, (c&7)^(r&7)))
  const int r0 = c0 >> 3, j0 = (c0 & 7) ^ (r0 & 7);
  const int r1 = c1 >> 3, j1 = (c1 & 7) ^ (r1 & 7);
  const bf16* kp0 = Kp + kbase + (size_t)r0 * 1024 + j0 * 8;
  const bf16* kp1 = Kp + kbase + (size_t)r1 * 1024 + j1 * 8;
  // V source: identity (global buffer already in LDS-image chunk order)
  const size_t vbase16 = (size_t)((b * 16 + h) * 32) * 512;
  const bf16* vp0 = Vt + (vbase16 + c0) * 8;
  const bf16* vp1 = Vt + (vbase16 + c1) * 8;

  // Q fragments (B-operand of QK: n=la -> qrow, k=qa*8+j -> d); pre-scaled
  bf16x8 qf[2];
  for (int kk = 0; kk < 2; ++kk)
    qf[kk] = *(const bf16x8*)&Qp[(size_t)(b * 2048 + q0 + la) * 1024 + h * 64 + kk * 32 + qa * 8];

  bf16x4 ones4;
  for (int j = 0; j < 4; ++j) ones4[j] = (bf16)1.0f;

  // V fragment chunk signature: slot%8 = la&7 -> conflict-free b128
  const int vsig = (la & 7) + 8 * (qa + 4 * (la >> 3));

  f32x4 oacc[5];  // O^T d-tiles [0..3] + l [4]; col = la = q
  for (int d = 0; d < 5; ++d) oacc[d] = (f32x4){0.f, 0.f, 0.f, 0.f};

  // preamble: stage tile 0 into buffer 0
  async_load16(kp0, &Kb[0][cb0 * 8]);
  async_load16(kp1, &Kb[0][cb1 * 8]);
  async_load16(vp0, &Vb[0][cb0 * 8]);
  async_load16(vp1, &Vb[0][cb1 * 8]);
  unsigned long long mv = mrow[0];
  __syncthreads();

  for (int kt = 0; kt < 32; ++kt) {
    const int p = kt & 1;
    const bf16* Kc = Kb[p];
    const bf16* Vc = Vb[p];

    // prefetch tile kt+1 into buffer p^1 (in flight the whole iteration)
    unsigned long long mvn = 0;
    if (kt < 31) {
      bf16* Kn = Kb[p ^ 1];
      bf16* Vn = Vb[p ^ 1];
      kp0 += 64 * 1024; kp1 += 64 * 1024;  // next 64 K-rows
      vp0 += 4096;      vp1 += 4096;       // next tile (linear chunk stream)
      async_load16(kp0, &Kn[cb0 * 8]);
      async_load16(kp1, &Kn[cb1 * 8]);
      async_load16(vp0, &Vn[cb0 * 8]);
      async_load16(vp1, &Vn[cb1 * 8]);
      mvn = mrow[kt + 1];
    }

    // ---- S^T = K·Q^T : 64 kcols x 16 q (swizzled LDS reads) ----
    f32x4 s[4];
    for (int nt = 0; nt < 4; ++nt) s[nt] = (f32x4){0.f, 0.f, 0.f, 0.f};
#pragma unroll
    for (int kk = 0; kk < 2; ++kk)
#pragma unroll
      for (int nt = 0; nt < 4; ++nt) {
        const bf16x8 kf = *(const bf16x8*)&Kc[(nt * 16 + la) * 64 + (((kk * 4 + qa) ^ la7) * 8)];
        s[nt] = MFMA_BF16(kf, qf[kk], s[nt]);
      }

    // ---- V fragments: 8x ds_read_b128, conflict-free, independent of softmax
    bf16x8 vv[2][4];
#pragma unroll
    for (int dt2 = 0; dt2 < 2; ++dt2)
#pragma unroll
      for (int nt = 0; nt < 4; ++nt)
        vv[dt2][nt] = *(const bf16x8*)&Vc[((dt2 * 4 + nt) * 64 + vsig) * 8];

    // ---- fixed-base softmax: p = bits(exp2(s)) & sbfe(word, off+r, 1) ----
    const unsigned long long mvs = mv >> (qa * 4);
    const uint32_t mlo = (uint32_t)mvs, mhi = (uint32_t)(mvs >> 32);
    bf16x4 pfr[4];
#pragma unroll
    for (int nt = 0; nt < 4; ++nt) {
      const uint32_t word = (nt & 2) ? mhi : mlo;
      const int off = (nt & 1) * 16;
#pragma unroll
      for (int r = 0; r < 4; ++r) {
        const float e = exp2f(s[nt][r]);
        const uint32_t msk = (uint32_t)__builtin_amdgcn_sbfe((int)word, off + r, 1);
        pfr[nt][r] = (bf16)__builtin_bit_cast(float, __builtin_bit_cast(uint32_t, e) & msk);
      }
    }

    // ---- PV: O^T += V^T·P^T, l += 1^T·P^T — all in-register ----
#pragma unroll
    for (int nt = 0; nt < 4; ++nt) {
#pragma unroll
      for (int dt2 = 0; dt2 < 2; ++dt2) {
        const bf16x4 lo = __builtin_shufflevector(vv[dt2][nt], vv[dt2][nt], 0, 1, 2, 3);
        const bf16x4 hi = __builtin_shufflevector(vv[dt2][nt], vv[dt2][nt], 4, 5, 6, 7);
        oacc[2 * dt2]     = mfma16(lo, pfr[nt], oacc[2 * dt2]);
        oacc[2 * dt2 + 1] = mfma16(hi, pfr[nt], oacc[2 * dt2 + 1]);
      }
      oacc[4] = mfma16(ones4, pfr[nt], oacc[4]);
    }

    mv = mvn;
    __syncthreads();  // recycle buffer p; drains prefetch vmcnt for p^1
  }

  // ---- epilogue: O = O^T / l ----
  const float rl = 1.0f / oacc[4][0];
  for (int dt = 0; dt < 4; ++dt) {
    bf16x4 o4;
    for (int r = 0; r < 4; ++r) o4[r] = (bf16)(oacc[dt][r] * rl);
    *(bf16x4*)&AO[(size_t)(b * 2048 + q0 + la) * 1024 + h * 64 + dt * 16 + qa * 4] = o4;
  }
}

// ---------------------------------------------------------------------------
extern "C" void kernel_launch(void* const* d_in, const int* in_sizes, int n_in,
                              void* d_out, int out_size, void* d_ws, size_t ws_size,
                              hipStream_t stream) {
  const float* q    = (const float*)d_in[0];
  const float* k    = (const float*)d_in[1];
  const float* v    = (const float*)d_in[2];
  const int*   mask = (const int*)d_in[3];
  const float* wq   = (const float*)d_in[4];
  const float* wk   = (const float*)d_in[5];
  const float* wv   = (const float*)d_in[6];
  const float* wo   = (const float*)d_in[7];
  const float* bq   = (const float*)d_in[8];
  const float* bk   = (const float*)d_in[9];
  const float* bv   = (const float*)d_in[10];
  const float* bo   = (const float*)d_in[11];

  const size_t M4 = (size_t)4 * 1024 * 1024, M1 = (size_t)1024 * 1024;
  bf16* qb  = (bf16*)d_ws;        // becomes AO after projections
  bf16* kb  = qb + M4;
  bf16* vb  = kb + M4;
  bf16* wqb = vb + M4;
  bf16* wkb = wqb + M1;
  bf16* wvb = wkb + M1;
  bf16* wob = wvb + M1;
  bf16* Qp  = wob + M1;
  bf16* Kp  = Qp + M4;
  bf16* Vt  = Kp + M4;
  unsigned long long* mb = (unsigned long long*)(Vt + M4);
  bf16* AO  = qb;
  float* out = (float*)d_out;

  const float QSCALE = 0.18033688011112042f;  // (1/8) * log2(e)

  cvt_pack_kernel<<<dim3(1024, 8), dim3(256), 0, stream>>>(
      q, k, v, wq, wk, wv, wo, qb, kb, vb, wqb, wkb, wvb, wob, mask, mb);
  gemm_bt_bias<<<dim3(32, 8, 3), dim3(256), 0, stream>>>(
      qb, kb, vb, wqb, wkb, wvb, bq, bk, bv, Qp, Kp, Vt, nullptr, 1024, 1024, 2, 0, QSCALE);
  attn_kernel<<<dim3(32, 32), dim3(256), 0, stream>>>(Qp, Kp, Vt, mb, AO);
  gemm_bt_bias<<<dim3(32, 8, 1), dim3(256), 0, stream>>>(
      AO, AO, AO, wob, wob, wob, bo, bo, bo, nullptr, nullptr, nullptr, out, 1024, 1024, -1, 1, 1.0f);
}

// Round 10
// 285.836 us; speedup vs baseline: 1.0117x; 1.0117x over previous
//
#include <hip/hip_runtime.h>
#include <hip/hip_bf16.h>
#include <stdint.h>

// ---------------------------------------------------------------------------
// CrossModalAttention: B=2, Tq=Tk=2048, DIM=1024, HEADS=16, HEAD_DIM=64
// f32 in/out; bf16 MFMA compute.
// R17 = R15 GEMM/cvt_pack + attn restructured to 8-wave blocks sharing one
// K/V tile: 512 thr = 8 waves x 16 q-rows (per-wave code identical to R14's
// proven attn), grid (16,32) = 512 blocks = 2/CU = 16 waves/CU (vs 10.5).
// Rationale: six attn variants plateau at 84-86us with MfmaUtil 29 /
// VALUBusy 61 / conflicts 0 / HBM 12% -- dependency-latency-bound; wave
// supply (not LDS, not instruction count) is the binding constraint.
// Staging: 1 K-chunk + 1 V-chunk per thread per tile (512 chunks each).
// sbfe softmax reverted (R16: neutral); cvt_pk asm blacklisted (R10 NaN).
// V-projection GEMM epilogue stores V^T in attn LDS-image chunk order
// (16B chunk = rows (d,d+16) x 4 tokens) so attn V staging is linear
// global_load_lds and V reads are conflict-free ds_read_b128.
// ---------------------------------------------------------------------------

typedef __bf16 bf16;
typedef __bf16 bf16x4 __attribute__((ext_vector_type(4)));
typedef __bf16 bf16x8 __attribute__((ext_vector_type(8)));
typedef float f32x4 __attribute__((ext_vector_type(4)));
typedef short s16x4 __attribute__((ext_vector_type(4)));

#define MFMA_BF16(a, b, c) __builtin_amdgcn_mfma_f32_16x16x32_bf16((a), (b), (c), 0, 0, 0)

__device__ __forceinline__ f32x4 mfma16(bf16x4 a, bf16x4 b, f32x4 c) {
  return __builtin_amdgcn_mfma_f32_16x16x16bf16_1k(
      __builtin_bit_cast(s16x4, a), __builtin_bit_cast(s16x4, b), c, 0, 0, 0);
}

// async global->LDS, 16B per lane (wave-uniform base, lane i at base+i*16)
__device__ __forceinline__ void async_load16(const void* g, void* l) {
  __builtin_amdgcn_global_load_lds((const __attribute__((address_space(1))) void*)g,
                                   (__attribute__((address_space(3))) void*)l, 16, 0, 0);
}

// ---------------------------------------------------------------------------
// 0) fused f32->bf16 conversion (z=0..6) + mask bit-pack (z=7).
//    grid = (1024, 8), grid-stride in each plane.
// ---------------------------------------------------------------------------
__global__ __launch_bounds__(256) void cvt_pack_kernel(
    const float* __restrict__ s0, const float* __restrict__ s1, const float* __restrict__ s2,
    const float* __restrict__ s3, const float* __restrict__ s4, const float* __restrict__ s5,
    const float* __restrict__ s6,
    bf16* __restrict__ d0, bf16* __restrict__ d1, bf16* __restrict__ d2,
    bf16* __restrict__ d3, bf16* __restrict__ d4, bf16* __restrict__ d5,
    bf16* __restrict__ d6,
    const int* __restrict__ mask, unsigned long long* __restrict__ bits) {
  const int z = blockIdx.y;
  if (z == 7) {
    // mask pack: t indexes int4 -> values 4t..4t+3 -> bits 4*(t&15)+j of
    // word t>>4. stride is a multiple of 16 so t&15 == tid&15 invariantly.
    const int total4 = 8388608 / 4;
    const int stride = gridDim.x * 256;
    for (int t = blockIdx.x * 256 + threadIdx.x; t < total4; t += stride) {
      const int4 v = ((const int4*)mask)[t];
      uint32_t wrd = (v.x != 0 ? 1u : 0u) | (v.y != 0 ? 2u : 0u) |
                     (v.z != 0 ? 4u : 0u) | (v.w != 0 ? 8u : 0u);
      wrd <<= 4 * (threadIdx.x & 7);
      wrd |= __shfl_xor((int)wrd, 1);
      wrd |= __shfl_xor((int)wrd, 2);
      wrd |= __shfl_xor((int)wrd, 4);
      const uint32_t other = (uint32_t)__shfl_xor((int)wrd, 8);
      if ((threadIdx.x & 15) == 0)
        bits[t >> 4] = (unsigned long long)wrd | ((unsigned long long)other << 32);
    }
    return;
  }
  const float* s = (z == 0) ? s0 : (z == 1) ? s1 : (z == 2) ? s2 : (z == 3) ? s3
                   : (z == 4) ? s4 : (z == 5) ? s5 : s6;
  bf16* d = (z == 0) ? d0 : (z == 1) ? d1 : (z == 2) ? d2 : (z == 3) ? d3
            : (z == 4) ? d4 : (z == 5) ? d5 : d6;
  const int n4 = (z < 3) ? (4 * 1024 * 1024 / 4) : (1024 * 1024 / 4);
  const int stride = gridDim.x * 256;
  for (int i = blockIdx.x * 256 + threadIdx.x; i < n4; i += stride) {
    const float4 v = ((const float4*)s)[i];
    bf16x4 o;
    o[0] = (bf16)v.x; o[1] = (bf16)v.y; o[2] = (bf16)v.z; o[3] = (bf16)v.w;
    ((bf16x4*)d)[i] = o;
  }
}

// ---------------------------------------------------------------------------
// 2/4) GEMM C[m,n] = sum_k X[m,k]*W[n,k] + bias[n]  (m97 K-loop)
//      qs: extra output scale applied only for z==0 bf16 path (Q projection).
//      z==vz: V^T written in attn LDS-image chunk layout (see header).
// ---------------------------------------------------------------------------
__global__ __launch_bounds__(256) void gemm_bt_bias(
    const bf16* __restrict__ X0, const bf16* __restrict__ X1, const bf16* __restrict__ X2,
    const bf16* __restrict__ W0, const bf16* __restrict__ W1, const bf16* __restrict__ W2,
    const float* __restrict__ Bi0, const float* __restrict__ Bi1, const float* __restrict__ Bi2,
    bf16* __restrict__ O0, bf16* __restrict__ O1, bf16* __restrict__ O2,
    float* __restrict__ OF, int K, int N, int vz, int f32out, float qs) {
  const int z = blockIdx.z;
  const bf16* X   = (z == 0) ? X0  : (z == 1) ? X1  : X2;
  const bf16* W   = (z == 0) ? W0  : (z == 1) ? W1  : W2;
  const float* Bi = (z == 0) ? Bi0 : (z == 1) ? Bi1 : Bi2;
  bf16* O         = (z == 0) ? O0  : (z == 1) ? O1  : O2;

  __shared__ __align__(16) unsigned char smem_raw[34816];
  bf16* As  = (bf16*)smem_raw;
  bf16* Bs  = As + 128 * 64;
  bf16* Tt  = (bf16*)smem_raw;   // bf16 tile, stride 136
  float* Tf = (float*)smem_raw;  // f32 half-tile (64 rows), stride 132

  const int tid = threadIdx.x;
  const int lane = tid & 63;
  const int w = tid >> 6;
  const int la = lane & 15;
  const int qa = lane >> 4;
  const int m0 = blockIdx.x * 128;
  const int n0 = blockIdx.y * 128;
  const int wm = (w & 1) * 64;
  const int wn = (w >> 1) * 64;

  f32x4 acc[4][4];
  for (int i = 0; i < 4; ++i)
    for (int j = 0; j < 4; ++j) acc[i][j] = (f32x4){0.f, 0.f, 0.f, 0.f};

  for (int k0 = 0; k0 < K; k0 += 64) {
    for (int i = 0; i < 4; ++i) {
      const int cb = i * 256 + w * 64;
      const int c = cb + lane;
      const int row = c >> 3;
      const int cc = (c & 7) * 8;
      async_load16(X + (size_t)(m0 + row) * K + k0 + cc, As + (size_t)cb * 8);
      async_load16(W + (size_t)(n0 + row) * K + k0 + cc, Bs + (size_t)cb * 8);
    }
    __syncthreads();
    for (int kk = 0; kk < 64; kk += 32) {
      bf16x8 af[4], bfr[4];
      for (int mt = 0; mt < 4; ++mt)
        af[mt] = *(const bf16x8*)&As[(wm + mt * 16 + la) * 64 + kk + qa * 8];
      for (int nt = 0; nt < 4; ++nt)
        bfr[nt] = *(const bf16x8*)&Bs[(wn + nt * 16 + la) * 64 + kk + qa * 8];
      for (int mt = 0; mt < 4; ++mt)
        for (int nt = 0; nt < 4; ++nt)
          acc[mt][nt] = MFMA_BF16(af[mt], bfr[nt], acc[mt][nt]);
    }
    __syncthreads();
  }

  if (f32out) {
    for (int pass = 0; pass < 2; ++pass) {
      if ((w & 1) == pass) {
        for (int mt = 0; mt < 4; ++mt)
          for (int nt = 0; nt < 4; ++nt)
            for (int r = 0; r < 4; ++r) {
              const int rl = mt * 16 + qa * 4 + r;
              const int cl = wn + nt * 16 + la;
              Tf[rl * 132 + cl] = acc[mt][nt][r] + Bi[n0 + cl];
            }
      }
      __syncthreads();
      for (int i = 0; i < 8; ++i) {
        const int rl = i * 8 + (tid >> 5);
        const int cl = (tid & 31) * 4;
        const float4 vv = *(const float4*)&Tf[rl * 132 + cl];
        *(float4*)&OF[(size_t)(m0 + pass * 64 + rl) * N + n0 + cl] = vv;
      }
      __syncthreads();
    }
  } else if (z != vz) {
    const float sc = (z == 0) ? qs : 1.0f;
    for (int mt = 0; mt < 4; ++mt)
      for (int nt = 0; nt < 4; ++nt)
        for (int r = 0; r < 4; ++r) {
          const int rl = wm + mt * 16 + qa * 4 + r;
          const int cl = wn + nt * 16 + la;
          Tt[rl * 136 + cl] = (bf16)((acc[mt][nt][r] + Bi[n0 + cl]) * sc);
        }
    __syncthreads();
    for (int i = 0; i < 8; ++i) {
      const int rl = i * 16 + (tid >> 4);
      const int cc = (tid & 15) * 8;
      *(bf16x8*)&O[(size_t)(m0 + rl) * N + n0 + cc] = *(const bf16x8*)&Tt[rl * 136 + cc];
    }
  } else {
    // V^T in LDS (d-major), then chunked attn LDS-image layout to global.
    for (int mt = 0; mt < 4; ++mt)
      for (int nt = 0; nt < 4; ++nt)
        for (int r = 0; r < 4; ++r) {
          const int rl = wm + mt * 16 + qa * 4 + r;
          const int cl = wn + nt * 16 + la;
          Tt[cl * 136 + rl] = (bf16)(acc[mt][nt][r] + Bi[n0 + cl]);
        }
    __syncthreads();
    const int bb = m0 >> 11;
    const int kt0 = (m0 & 2047) >> 6;  // first of 2 token-tiles in this block
    const int h0 = n0 >> 6;            // first of 2 heads in this block
    // 2048 chunks of 16B: gi = (hb<<10)|(ktb<<9)|c ; c = (dt2*4+nt)*64 + sig,
    // sig = (la&7) + 8*(qa + 4*(la>>3)). Chunk = rows {dt2*32+lac, +16} x
    // tokens ktb*64 + nt*16 + qa*4 + 0..3.
    for (int i = 0; i < 8; ++i) {
      const int gi = i * 256 + tid;
      const int c = gi & 511;
      const int ktb = (gi >> 9) & 1;
      const int hb = gi >> 10;
      const int dt2 = (c >> 8) & 1;
      const int ntc = (c >> 6) & 3;
      const int tq = (c >> 3) & 7;
      const int qac = tq & 3;
      const int lac = ((tq >> 2) << 3) + (c & 7);
      const int clA = hb * 64 + dt2 * 32 + lac;
      const int rlb = ktb * 64 + ntc * 16 + qac * 4;
      const bf16x4 lo4 = *(const bf16x4*)&Tt[clA * 136 + rlb];
      const bf16x4 hi4 = *(const bf16x4*)&Tt[(clA + 16) * 136 + rlb];
      bf16x8 outc;
      for (int j = 0; j < 4; ++j) { outc[j] = lo4[j]; outc[j + 4] = hi4[j]; }
      const size_t g16 = ((size_t)((bb * 16 + h0 + hb) * 32) + kt0 + ktb) * 512 + c;
      *(bf16x8*)&O[g16 * 8] = outc;
    }
  }
}

// ---------------------------------------------------------------------------
// 3) fused attention (R17). grid = (Tq/128, B*H), 8 waves x 16 q-rows
//    sharing one K/V tile pair, KT=64, 32 iterations, one barrier/iter,
//    async double-buffer. Per-wave code identical to R14. Staging: one
//    K-chunk + one V-chunk per thread per tile (512 chunks each). K tile
//    XOR-swizzled (pre-swizzled global source); V tile linear (global buffer
//    is the LDS image), 8x conflict-free ds_read_b128 per wave. Softmax: R9
//    form (p = exp2(s), Q pre-scaled; float bit-mask mul).
// ---------------------------------------------------------------------------
__global__ __launch_bounds__(512, 4) void attn_kernel(
    const bf16* __restrict__ Qp, const bf16* __restrict__ Kp, const bf16* __restrict__ Vt,
    const unsigned long long* __restrict__ mbits, bf16* __restrict__ AO) {
  __shared__ bf16 Kb[2][64 * 64];  // [kcol][d], XOR-swizzled chunks
  __shared__ bf16 Vb[2][64 * 64];  // chunk-image layout (see GEMM epilogue)

  const int tid = threadIdx.x;
  const int lane = tid & 63;
  const int w = tid >> 6;          // 0..7
  const int la = lane & 15;
  const int qa = lane >> 4;
  const int la7 = la & 7;
  const int b = blockIdx.y >> 4;
  const int h = blockIdx.y & 15;
  const int q0 = blockIdx.x * 128 + w * 16;  // this wave's 16 q-rows

  const size_t kbase = (size_t)(b * 2048) * 1024 + h * 64;
  const unsigned long long* mrow = mbits + ((size_t)(b * 2048 + q0 + la)) * 32;

  // staging geometry: 512 chunks of 16B per tile, ONE per thread
  const int c0 = tid;
  // K source: XOR-swizzled chunks (slot c holds global chunk (r, (c&7)^(r&7)))
  const int r0 = c0 >> 3, j0 = (c0 & 7) ^ (r0 & 7);
  const bf16* kp0 = Kp + kbase + (size_t)r0 * 1024 + j0 * 8;
  // V source: identity (global buffer already in LDS-image chunk order)
  const size_t vbase16 = (size_t)((b * 16 + h) * 32) * 512;
  const bf16* vp0 = Vt + (vbase16 + c0) * 8;

  // Q fragments (B-operand of QK: n=la -> qrow, k=qa*8+j -> d); pre-scaled
  bf16x8 qf[2];
  for (int kk = 0; kk < 2; ++kk)
    qf[kk] = *(const bf16x8*)&Qp[(size_t)(b * 2048 + q0 + la) * 1024 + h * 64 + kk * 32 + qa * 8];

  bf16x4 ones4;
  for (int j = 0; j < 4; ++j) ones4[j] = (bf16)1.0f;

  // V fragment chunk signature: slot%8 = la&7 -> conflict-free b128
  const int vsig = (la & 7) + 8 * (qa + 4 * (la >> 3));

  f32x4 oacc[5];  // O^T d-tiles [0..3] + l [4]; col = la = q
  for (int d = 0; d < 5; ++d) oacc[d] = (f32x4){0.f, 0.f, 0.f, 0.f};

  // preamble: stage tile 0 into buffer 0
  async_load16(kp0, &Kb[0][c0 * 8]);
  async_load16(vp0, &Vb[0][c0 * 8]);
  unsigned long long mv = mrow[0];
  __syncthreads();

  for (int kt = 0; kt < 32; ++kt) {
    const int p = kt & 1;
    const bf16* Kc = Kb[p];
    const bf16* Vc = Vb[p];

    // prefetch tile kt+1 into buffer p^1 (in flight the whole iteration)
    unsigned long long mvn = 0;
    if (kt < 31) {
      bf16* Kn = Kb[p ^ 1];
      bf16* Vn = Vb[p ^ 1];
      kp0 += 64 * 1024;  // next 64 K-rows
      vp0 += 4096;       // next tile (linear chunk stream)
      async_load16(kp0, &Kn[c0 * 8]);
      async_load16(vp0, &Vn[c0 * 8]);
      mvn = mrow[kt + 1];
    }

    // ---- S^T = K·Q^T : 64 kcols x 16 q (swizzled LDS reads) ----
    f32x4 s[4];
    for (int nt = 0; nt < 4; ++nt) s[nt] = (f32x4){0.f, 0.f, 0.f, 0.f};
#pragma unroll
    for (int kk = 0; kk < 2; ++kk)
#pragma unroll
      for (int nt = 0; nt < 4; ++nt) {
        const bf16x8 kf = *(const bf16x8*)&Kc[(nt * 16 + la) * 64 + (((kk * 4 + qa) ^ la7) * 8)];
        s[nt] = MFMA_BF16(kf, qf[kk], s[nt]);
      }

    // ---- V fragments: 8x ds_read_b128, conflict-free, independent of softmax
    bf16x8 vv[2][4];
#pragma unroll
    for (int dt2 = 0; dt2 < 2; ++dt2)
#pragma unroll
      for (int nt = 0; nt < 4; ++nt)
        vv[dt2][nt] = *(const bf16x8*)&Vc[((dt2 * 4 + nt) * 64 + vsig) * 8];

    // ---- fixed-base softmax (R9 form): p = maskbit * exp2(s) ----
    const unsigned long long mvs = mv >> (qa * 4);
    const uint32_t mlo = (uint32_t)mvs, mhi = (uint32_t)(mvs >> 32);
    bf16x4 pfr[4];
#pragma unroll
    for (int nt = 0; nt < 4; ++nt) {
      const uint32_t mw = ((nt & 2) ? mhi : mlo) >> ((nt & 1) * 16);
#pragma unroll
      for (int r = 0; r < 4; ++r) {
        const float bitf = (float)((mw >> r) & 1u);
        pfr[nt][r] = (bf16)(bitf * exp2f(s[nt][r]));
      }
    }

    // ---- PV: O^T += V^T·P^T, l += 1^T·P^T — all in-register ----
#pragma unroll
    for (int nt = 0; nt < 4; ++nt) {
#pragma unroll
      for (int dt2 = 0; dt2 < 2; ++dt2) {
        const bf16x4 lo = __builtin_shufflevector(vv[dt2][nt], vv[dt2][nt], 0, 1, 2, 3);
        const bf16x4 hi = __builtin_shufflevector(vv[dt2][nt], vv[dt2][nt], 4, 5, 6, 7);
        oacc[2 * dt2]     = mfma16(lo, pfr[nt], oacc[2 * dt2]);
        oacc[2 * dt2 + 1] = mfma16(hi, pfr[nt], oacc[2 * dt2 + 1]);
      }
      oacc[4] = mfma16(ones4, pfr[nt], oacc[4]);
    }

    mv = mvn;
    __syncthreads();  // recycle buffer p; drains prefetch vmcnt for p^1
  }

  // ---- epilogue: O = O^T / l ----
  const float rl = 1.0f / oacc[4][0];
  for (int dt = 0; dt < 4; ++dt) {
    bf16x4 o4;
    for (int r = 0; r < 4; ++r) o4[r] = (bf16)(oacc[dt][r] * rl);
    *(bf16x4*)&AO[(size_t)(b * 2048 + q0 + la) * 1024 + h * 64 + dt * 16 + qa * 4] = o4;
  }
}

// ---------------------------------------------------------------------------
extern "C" void kernel_launch(void* const* d_in, const int* in_sizes, int n_in,
                              void* d_out, int out_size, void* d_ws, size_t ws_size,
                              hipStream_t stream) {
  const float* q    = (const float*)d_in[0];
  const float* k    = (const float*)d_in[1];
  const float* v    = (const float*)d_in[2];
  const int*   mask = (const int*)d_in[3];
  const float* wq   = (const float*)d_in[4];
  const float* wk   = (const float*)d_in[5];
  const float* wv   = (const float*)d_in[6];
  const float* wo   = (const float*)d_in[7];
  const float* bq   = (const float*)d_in[8];
  const float* bk   = (const float*)d_in[9];
  const float* bv   = (const float*)d_in[10];
  const float* bo   = (const float*)d_in[11];

  const size_t M4 = (size_t)4 * 1024 * 1024, M1 = (size_t)1024 * 1024;
  bf16* qb  = (bf16*)d_ws;        // becomes AO after projections
  bf16* kb  = qb + M4;
  bf16* vb  = kb + M4;
  bf16* wqb = vb + M4;
  bf16* wkb = wqb + M1;
  bf16* wvb = wkb + M1;
  bf16* wob = wvb + M1;
  bf16* Qp  = wob + M1;
  bf16* Kp  = Qp + M4;
  bf16* Vt  = Kp + M4;
  unsigned long long* mb = (unsigned long long*)(Vt + M4);
  bf16* AO  = qb;
  float* out = (float*)d_out;

  const float QSCALE = 0.18033688011112042f;  // (1/8) * log2(e)

  cvt_pack_kernel<<<dim3(1024, 8), dim3(256), 0, stream>>>(
      q, k, v, wq, wk, wv, wo, qb, kb, vb, wqb, wkb, wvb, wob, mask, mb);
  gemm_bt_bias<<<dim3(32, 8, 3), dim3(256), 0, stream>>>(
      qb, kb, vb, wqb, wkb, wvb, bq, bk, bv, Qp, Kp, Vt, nullptr, 1024, 1024, 2, 0, QSCALE);
  attn_kernel<<<dim3(16, 32), dim3(512), 0, stream>>>(Qp, Kp, Vt, mb, AO);
  gemm_bt_bias<<<dim3(32, 8, 1), dim3(256), 0, stream>>>(
      AO, AO, AO, wob, wob, wob, bo, bo, bo, nullptr, nullptr, nullptr, out, 1024, 1024, -1, 1, 1.0f);
}

// Round 11
// 282.286 us; speedup vs baseline: 1.0244x; 1.0126x over previous
//
#include <hip/hip_runtime.h>
#include <hip/hip_bf16.h>
#include <stdint.h>

// ---------------------------------------------------------------------------
// CrossModalAttention: B=2, Tq=Tk=2048, DIM=1024, HEADS=16, HEAD_DIM=64
// f32 in/out; bf16 MFMA compute.
// R18 = R17 + mask folded into QK accumulator init: s[nt] initialized to
// (maskbit ? 0 : -200.0f) via sbfe+AND before the MFMA, softmax is bare
// p = exp2(s). Masked: exp2(-200+s) underflows f32 -> bf16 0, bit-identical
// to the old explicit mask-mul. Deletes 16 movs + 16x(bfe+cvt+mul) per iter,
// adds 2 inverts + 16x(sbfe+and): ~-30 VALU cyc/iter on a kernel measured at
// ~90% combined issue (MfmaUtil 29.7 + VALUBusy 60.1) -- VALU-issue-bound.
// attn structure otherwise R17 (8-wave blocks, shared K/V tile, 82.0us);
// cvt_pack / GEMMs byte-identical.
// V-projection GEMM epilogue stores V^T in attn LDS-image chunk order
// (16B chunk = rows (d,d+16) x 4 tokens) so attn V staging is linear
// global_load_lds and V reads are conflict-free ds_read_b128.
// ---------------------------------------------------------------------------

typedef __bf16 bf16;
typedef __bf16 bf16x4 __attribute__((ext_vector_type(4)));
typedef __bf16 bf16x8 __attribute__((ext_vector_type(8)));
typedef float f32x4 __attribute__((ext_vector_type(4)));
typedef short s16x4 __attribute__((ext_vector_type(4)));

#define MFMA_BF16(a, b, c) __builtin_amdgcn_mfma_f32_16x16x32_bf16((a), (b), (c), 0, 0, 0)

__device__ __forceinline__ f32x4 mfma16(bf16x4 a, bf16x4 b, f32x4 c) {
  return __builtin_amdgcn_mfma_f32_16x16x16bf16_1k(
      __builtin_bit_cast(s16x4, a), __builtin_bit_cast(s16x4, b), c, 0, 0, 0);
}

// async global->LDS, 16B per lane (wave-uniform base, lane i at base+i*16)
__device__ __forceinline__ void async_load16(const void* g, void* l) {
  __builtin_amdgcn_global_load_lds((const __attribute__((address_space(1))) void*)g,
                                   (__attribute__((address_space(3))) void*)l, 16, 0, 0);
}

// ---------------------------------------------------------------------------
// 0) fused f32->bf16 conversion (z=0..6) + mask bit-pack (z=7).
//    grid = (1024, 8), grid-stride in each plane.
// ---------------------------------------------------------------------------
__global__ __launch_bounds__(256) void cvt_pack_kernel(
    const float* __restrict__ s0, const float* __restrict__ s1, const float* __restrict__ s2,
    const float* __restrict__ s3, const float* __restrict__ s4, const float* __restrict__ s5,
    const float* __restrict__ s6,
    bf16* __restrict__ d0, bf16* __restrict__ d1, bf16* __restrict__ d2,
    bf16* __restrict__ d3, bf16* __restrict__ d4, bf16* __restrict__ d5,
    bf16* __restrict__ d6,
    const int* __restrict__ mask, unsigned long long* __restrict__ bits) {
  const int z = blockIdx.y;
  if (z == 7) {
    // mask pack: t indexes int4 -> values 4t..4t+3 -> bits 4*(t&15)+j of
    // word t>>4. stride is a multiple of 16 so t&15 == tid&15 invariantly.
    const int total4 = 8388608 / 4;
    const int stride = gridDim.x * 256;
    for (int t = blockIdx.x * 256 + threadIdx.x; t < total4; t += stride) {
      const int4 v = ((const int4*)mask)[t];
      uint32_t wrd = (v.x != 0 ? 1u : 0u) | (v.y != 0 ? 2u : 0u) |
                     (v.z != 0 ? 4u : 0u) | (v.w != 0 ? 8u : 0u);
      wrd <<= 4 * (threadIdx.x & 7);
      wrd |= __shfl_xor((int)wrd, 1);
      wrd |= __shfl_xor((int)wrd, 2);
      wrd |= __shfl_xor((int)wrd, 4);
      const uint32_t other = (uint32_t)__shfl_xor((int)wrd, 8);
      if ((threadIdx.x & 15) == 0)
        bits[t >> 4] = (unsigned long long)wrd | ((unsigned long long)other << 32);
    }
    return;
  }
  const float* s = (z == 0) ? s0 : (z == 1) ? s1 : (z == 2) ? s2 : (z == 3) ? s3
                   : (z == 4) ? s4 : (z == 5) ? s5 : s6;
  bf16* d = (z == 0) ? d0 : (z == 1) ? d1 : (z == 2) ? d2 : (z == 3) ? d3
            : (z == 4) ? d4 : (z == 5) ? d5 : d6;
  const int n4 = (z < 3) ? (4 * 1024 * 1024 / 4) : (1024 * 1024 / 4);
  const int stride = gridDim.x * 256;
  for (int i = blockIdx.x * 256 + threadIdx.x; i < n4; i += stride) {
    const float4 v = ((const float4*)s)[i];
    bf16x4 o;
    o[0] = (bf16)v.x; o[1] = (bf16)v.y; o[2] = (bf16)v.z; o[3] = (bf16)v.w;
    ((bf16x4*)d)[i] = o;
  }
}

// ---------------------------------------------------------------------------
// 2/4) GEMM C[m,n] = sum_k X[m,k]*W[n,k] + bias[n]  (m97 K-loop)
//      qs: extra output scale applied only for z==0 bf16 path (Q projection).
//      z==vz: V^T written in attn LDS-image chunk layout (see header).
// ---------------------------------------------------------------------------
__global__ __launch_bounds__(256) void gemm_bt_bias(
    const bf16* __restrict__ X0, const bf16* __restrict__ X1, const bf16* __restrict__ X2,
    const bf16* __restrict__ W0, const bf16* __restrict__ W1, const bf16* __restrict__ W2,
    const float* __restrict__ Bi0, const float* __restrict__ Bi1, const float* __restrict__ Bi2,
    bf16* __restrict__ O0, bf16* __restrict__ O1, bf16* __restrict__ O2,
    float* __restrict__ OF, int K, int N, int vz, int f32out, float qs) {
  const int z = blockIdx.z;
  const bf16* X   = (z == 0) ? X0  : (z == 1) ? X1  : X2;
  const bf16* W   = (z == 0) ? W0  : (z == 1) ? W1  : W2;
  const float* Bi = (z == 0) ? Bi0 : (z == 1) ? Bi1 : Bi2;
  bf16* O         = (z == 0) ? O0  : (z == 1) ? O1  : O2;

  __shared__ __align__(16) unsigned char smem_raw[34816];
  bf16* As  = (bf16*)smem_raw;
  bf16* Bs  = As + 128 * 64;
  bf16* Tt  = (bf16*)smem_raw;   // bf16 tile, stride 136
  float* Tf = (float*)smem_raw;  // f32 half-tile (64 rows), stride 132

  const int tid = threadIdx.x;
  const int lane = tid & 63;
  const int w = tid >> 6;
  const int la = lane & 15;
  const int qa = lane >> 4;
  const int m0 = blockIdx.x * 128;
  const int n0 = blockIdx.y * 128;
  const int wm = (w & 1) * 64;
  const int wn = (w >> 1) * 64;

  f32x4 acc[4][4];
  for (int i = 0; i < 4; ++i)
    for (int j = 0; j < 4; ++j) acc[i][j] = (f32x4){0.f, 0.f, 0.f, 0.f};

  for (int k0 = 0; k0 < K; k0 += 64) {
    for (int i = 0; i < 4; ++i) {
      const int cb = i * 256 + w * 64;
      const int c = cb + lane;
      const int row = c >> 3;
      const int cc = (c & 7) * 8;
      async_load16(X + (size_t)(m0 + row) * K + k0 + cc, As + (size_t)cb * 8);
      async_load16(W + (size_t)(n0 + row) * K + k0 + cc, Bs + (size_t)cb * 8);
    }
    __syncthreads();
    for (int kk = 0; kk < 64; kk += 32) {
      bf16x8 af[4], bfr[4];
      for (int mt = 0; mt < 4; ++mt)
        af[mt] = *(const bf16x8*)&As[(wm + mt * 16 + la) * 64 + kk + qa * 8];
      for (int nt = 0; nt < 4; ++nt)
        bfr[nt] = *(const bf16x8*)&Bs[(wn + nt * 16 + la) * 64 + kk + qa * 8];
      for (int mt = 0; mt < 4; ++mt)
        for (int nt = 0; nt < 4; ++nt)
          acc[mt][nt] = MFMA_BF16(af[mt], bfr[nt], acc[mt][nt]);
    }
    __syncthreads();
  }

  if (f32out) {
    for (int pass = 0; pass < 2; ++pass) {
      if ((w & 1) == pass) {
        for (int mt = 0; mt < 4; ++mt)
          for (int nt = 0; nt < 4; ++nt)
            for (int r = 0; r < 4; ++r) {
              const int rl = mt * 16 + qa * 4 + r;
              const int cl = wn + nt * 16 + la;
              Tf[rl * 132 + cl] = acc[mt][nt][r] + Bi[n0 + cl];
            }
      }
      __syncthreads();
      for (int i = 0; i < 8; ++i) {
        const int rl = i * 8 + (tid >> 5);
        const int cl = (tid & 31) * 4;
        const float4 vv = *(const float4*)&Tf[rl * 132 + cl];
        *(float4*)&OF[(size_t)(m0 + pass * 64 + rl) * N + n0 + cl] = vv;
      }
      __syncthreads();
    }
  } else if (z != vz) {
    const float sc = (z == 0) ? qs : 1.0f;
    for (int mt = 0; mt < 4; ++mt)
      for (int nt = 0; nt < 4; ++nt)
        for (int r = 0; r < 4; ++r) {
          const int rl = wm + mt * 16 + qa * 4 + r;
          const int cl = wn + nt * 16 + la;
          Tt[rl * 136 + cl] = (bf16)((acc[mt][nt][r] + Bi[n0 + cl]) * sc);
        }
    __syncthreads();
    for (int i = 0; i < 8; ++i) {
      const int rl = i * 16 + (tid >> 4);
      const int cc = (tid & 15) * 8;
      *(bf16x8*)&O[(size_t)(m0 + rl) * N + n0 + cc] = *(const bf16x8*)&Tt[rl * 136 + cc];
    }
  } else {
    // V^T in LDS (d-major), then chunked attn LDS-image layout to global.
    for (int mt = 0; mt < 4; ++mt)
      for (int nt = 0; nt < 4; ++nt)
        for (int r = 0; r < 4; ++r) {
          const int rl = wm + mt * 16 + qa * 4 + r;
          const int cl = wn + nt * 16 + la;
          Tt[cl * 136 + rl] = (bf16)(acc[mt][nt][r] + Bi[n0 + cl]);
        }
    __syncthreads();
    const int bb = m0 >> 11;
    const int kt0 = (m0 & 2047) >> 6;  // first of 2 token-tiles in this block
    const int h0 = n0 >> 6;            // first of 2 heads in this block
    // 2048 chunks of 16B: gi = (hb<<10)|(ktb<<9)|c ; c = (dt2*4+nt)*64 + sig,
    // sig = (la&7) + 8*(qa + 4*(la>>3)). Chunk = rows {dt2*32+lac, +16} x
    // tokens ktb*64 + nt*16 + qa*4 + 0..3.
    for (int i = 0; i < 8; ++i) {
      const int gi = i * 256 + tid;
      const int c = gi & 511;
      const int ktb = (gi >> 9) & 1;
      const int hb = gi >> 10;
      const int dt2 = (c >> 8) & 1;
      const int ntc = (c >> 6) & 3;
      const int tq = (c >> 3) & 7;
      const int qac = tq & 3;
      const int lac = ((tq >> 2) << 3) + (c & 7);
      const int clA = hb * 64 + dt2 * 32 + lac;
      const int rlb = ktb * 64 + ntc * 16 + qac * 4;
      const bf16x4 lo4 = *(const bf16x4*)&Tt[clA * 136 + rlb];
      const bf16x4 hi4 = *(const bf16x4*)&Tt[(clA + 16) * 136 + rlb];
      bf16x8 outc;
      for (int j = 0; j < 4; ++j) { outc[j] = lo4[j]; outc[j + 4] = hi4[j]; }
      const size_t g16 = ((size_t)((bb * 16 + h0 + hb) * 32) + kt0 + ktb) * 512 + c;
      *(bf16x8*)&O[g16 * 8] = outc;
    }
  }
}

// ---------------------------------------------------------------------------
// 3) fused attention (R18). grid = (Tq/128, B*H), 8 waves x 16 q-rows
//    sharing one K/V tile pair, KT=64, 32 iterations, one barrier/iter,
//    async double-buffer. Mask folded into QK accumulator init:
//    s_init = maskbit ? 0 : -200.0f (sbfe + AND), softmax = bare exp2.
//    K tile XOR-swizzled (pre-swizzled global source); V tile linear (global
//    buffer is the LDS image), 8x conflict-free ds_read_b128 per wave.
// ---------------------------------------------------------------------------
__global__ __launch_bounds__(512, 4) void attn_kernel(
    const bf16* __restrict__ Qp, const bf16* __restrict__ Kp, const bf16* __restrict__ Vt,
    const unsigned long long* __restrict__ mbits, bf16* __restrict__ AO) {
  __shared__ bf16 Kb[2][64 * 64];  // [kcol][d], XOR-swizzled chunks
  __shared__ bf16 Vb[2][64 * 64];  // chunk-image layout (see GEMM epilogue)

  const int tid = threadIdx.x;
  const int lane = tid & 63;
  const int w = tid >> 6;          // 0..7
  const int la = lane & 15;
  const int qa = lane >> 4;
  const int la7 = la & 7;
  const int b = blockIdx.y >> 4;
  const int h = blockIdx.y & 15;
  const int q0 = blockIdx.x * 128 + w * 16;  // this wave's 16 q-rows

  const size_t kbase = (size_t)(b * 2048) * 1024 + h * 64;
  const unsigned long long* mrow = mbits + ((size_t)(b * 2048 + q0 + la)) * 32;

  // staging geometry: 512 chunks of 16B per tile, ONE per thread
  const int c0 = tid;
  // K source: XOR-swizzled chunks (slot c holds global chunk (r, (c&7)^(r&7)))
  const int r0 = c0 >> 3, j0 = (c0 & 7) ^ (r0 & 7);
  const bf16* kp0 = Kp + kbase + (size_t)r0 * 1024 + j0 * 8;
  // V source: identity (global buffer already in LDS-image chunk order)
  const size_t vbase16 = (size_t)((b * 16 + h) * 32) * 512;
  const bf16* vp0 = Vt + (vbase16 + c0) * 8;

  // Q fragments (B-operand of QK: n=la -> qrow, k=qa*8+j -> d); pre-scaled
  bf16x8 qf[2];
  for (int kk = 0; kk < 2; ++kk)
    qf[kk] = *(const bf16x8*)&Qp[(size_t)(b * 2048 + q0 + la) * 1024 + h * 64 + kk * 32 + qa * 8];

  bf16x4 ones4;
  for (int j = 0; j < 4; ++j) ones4[j] = (bf16)1.0f;

  // V fragment chunk signature: slot%8 = la&7 -> conflict-free b128
  const int vsig = (la & 7) + 8 * (qa + 4 * (la >> 3));

  f32x4 oacc[5];  // O^T d-tiles [0..3] + l [4]; col = la = q
  for (int d = 0; d < 5; ++d) oacc[d] = (f32x4){0.f, 0.f, 0.f, 0.f};

  // preamble: stage tile 0 into buffer 0
  async_load16(kp0, &Kb[0][c0 * 8]);
  async_load16(vp0, &Vb[0][c0 * 8]);
  unsigned long long mv = mrow[0];
  __syncthreads();

  const uint32_t NEG_BIAS = 0xC3480000u;  // bits of -200.0f

  for (int kt = 0; kt < 32; ++kt) {
    const int p = kt & 1;
    const bf16* Kc = Kb[p];
    const bf16* Vc = Vb[p];

    // prefetch tile kt+1 into buffer p^1 (in flight the whole iteration)
    unsigned long long mvn = 0;
    if (kt < 31) {
      bf16* Kn = Kb[p ^ 1];
      bf16* Vn = Vb[p ^ 1];
      kp0 += 64 * 1024;  // next 64 K-rows
      vp0 += 4096;       // next tile (linear chunk stream)
      async_load16(kp0, &Kn[c0 * 8]);
      async_load16(vp0, &Vn[c0 * 8]);
      mvn = mrow[kt + 1];
    }

    // ---- accumulator init from mask: s = maskbit ? 0 : -200.0f ----
    const unsigned long long mvs = mv >> (qa * 4);
    const uint32_t nlo = ~(uint32_t)mvs, nhi = ~(uint32_t)(mvs >> 32);
    f32x4 s[4];
#pragma unroll
    for (int nt = 0; nt < 4; ++nt) {
      const uint32_t nword = (nt & 2) ? nhi : nlo;
      const int off = (nt & 1) * 16;
#pragma unroll
      for (int r = 0; r < 4; ++r) {
        // sbfe -> 0 (keep) or 0xFFFFFFFF (masked); AND with -200.0f bits
        const uint32_t mneg = (uint32_t)__builtin_amdgcn_sbfe((int)nword, off + r, 1);
        s[nt][r] = __builtin_bit_cast(float, mneg & NEG_BIAS);
      }
    }

    // ---- S^T = K·Q^T : 64 kcols x 16 q (swizzled LDS reads) ----
#pragma unroll
    for (int kk = 0; kk < 2; ++kk)
#pragma unroll
      for (int nt = 0; nt < 4; ++nt) {
        const bf16x8 kf = *(const bf16x8*)&Kc[(nt * 16 + la) * 64 + (((kk * 4 + qa) ^ la7) * 8)];
        s[nt] = MFMA_BF16(kf, qf[kk], s[nt]);
      }

    // ---- V fragments: 8x ds_read_b128, conflict-free, independent of softmax
    bf16x8 vv[2][4];
#pragma unroll
    for (int dt2 = 0; dt2 < 2; ++dt2)
#pragma unroll
      for (int nt = 0; nt < 4; ++nt)
        vv[dt2][nt] = *(const bf16x8*)&Vc[((dt2 * 4 + nt) * 64 + vsig) * 8];

    // ---- fixed-base softmax: p = exp2(s)  (mask already in s) ----
    bf16x4 pfr[4];
#pragma unroll
    for (int nt = 0; nt < 4; ++nt)
#pragma unroll
      for (int r = 0; r < 4; ++r)
        pfr[nt][r] = (bf16)exp2f(s[nt][r]);

    // ---- PV: O^T += V^T·P^T, l += 1^T·P^T — all in-register ----
#pragma unroll
    for (int nt = 0; nt < 4; ++nt) {
#pragma unroll
      for (int dt2 = 0; dt2 < 2; ++dt2) {
        const bf16x4 lo = __builtin_shufflevector(vv[dt2][nt], vv[dt2][nt], 0, 1, 2, 3);
        const bf16x4 hi = __builtin_shufflevector(vv[dt2][nt], vv[dt2][nt], 4, 5, 6, 7);
        oacc[2 * dt2]     = mfma16(lo, pfr[nt], oacc[2 * dt2]);
        oacc[2 * dt2 + 1] = mfma16(hi, pfr[nt], oacc[2 * dt2 + 1]);
      }
      oacc[4] = mfma16(ones4, pfr[nt], oacc[4]);
    }

    mv = mvn;
    __syncthreads();  // recycle buffer p; drains prefetch vmcnt for p^1
  }

  // ---- epilogue: O = O^T / l ----
  const float rl = 1.0f / oacc[4][0];
  for (int dt = 0; dt < 4; ++dt) {
    bf16x4 o4;
    for (int r = 0; r < 4; ++r) o4[r] = (bf16)(oacc[dt][r] * rl);
    *(bf16x4*)&AO[(size_t)(b * 2048 + q0 + la) * 1024 + h * 64 + dt * 16 + qa * 4] = o4;
  }
}

// ---------------------------------------------------------------------------
extern "C" void kernel_launch(void* const* d_in, const int* in_sizes, int n_in,
                              void* d_out, int out_size, void* d_ws, size_t ws_size,
                              hipStream_t stream) {
  const float* q    = (const float*)d_in[0];
  const float* k    = (const float*)d_in[1];
  const float* v    = (const float*)d_in[2];
  const int*   mask = (const int*)d_in[3];
  const float* wq   = (const float*)d_in[4];
  const float* wk   = (const float*)d_in[5];
  const float* wv   = (const float*)d_in[6];
  const float* wo   = (const float*)d_in[7];
  const float* bq   = (const float*)d_in[8];
  const float* bk   = (const float*)d_in[9];
  const float* bv   = (const float*)d_in[10];
  const float* bo   = (const float*)d_in[11];

  const size_t M4 = (size_t)4 * 1024 * 1024, M1 = (size_t)1024 * 1024;
  bf16* qb  = (bf16*)d_ws;        // becomes AO after projections
  bf16* kb  = qb + M4;
  bf16* vb  = kb + M4;
  bf16* wqb = vb + M4;
  bf16* wkb = wqb + M1;
  bf16* wvb = wkb + M1;
  bf16* wob = wvb + M1;
  bf16* Qp  = wob + M1;
  bf16* Kp  = Qp + M4;
  bf16* Vt  = Kp + M4;
  unsigned long long* mb = (unsigned long long*)(Vt + M4);
  bf16* AO  = qb;
  float* out = (float*)d_out;

  const float QSCALE = 0.18033688011112042f;  // (1/8) * log2(e)

  cvt_pack_kernel<<<dim3(1024, 8), dim3(256), 0, stream>>>(
      q, k, v, wq, wk, wv, wo, qb, kb, vb, wqb, wkb, wvb, wob, mask, mb);
  gemm_bt_bias<<<dim3(32, 8, 3), dim3(256), 0, stream>>>(
      qb, kb, vb, wqb, wkb, wvb, bq, bk, bv, Qp, Kp, Vt, nullptr, 1024, 1024, 2, 0, QSCALE);
  attn_kernel<<<dim3(16, 32), dim3(512), 0, stream>>>(Qp, Kp, Vt, mb, AO);
  gemm_bt_bias<<<dim3(32, 8, 1), dim3(256), 0, stream>>>(
      AO, AO, AO, wob, wob, wob, bo, bo, bo, nullptr, nullptr, nullptr, out, 1024, 1024, -1, 1, 1.0f);
}